// Round 3
// baseline (423.379 us; speedup 1.0000x reference)
//
#include <hip/hip_runtime.h>

typedef _Float16 f16;
typedef f16 half8 __attribute__((ext_vector_type(8)));
typedef float f32x4 __attribute__((ext_vector_type(4)));
typedef unsigned long long u64;
typedef unsigned int u32;
typedef unsigned short u16;

#define KD 8192
#define DIFF_OFF 4194304
#define EIND_OFF 4194305
#define PERP_OFF 4210689
#define LCAP 262144

// ws (<300KB, known-safe): best u64[16384]@0 | Fv@131072 | eev@196608 |
//   counts@229376 | dpart@262144 | eemax@266240 | cnt@266244
// d_out scratch (dead before k_out writes quantize):
//   xhT f16[16384][256]@0 (8MB) | ehT f16[8192][256]@8MB (4MB)
//   m1 u32[16384][32]@12MB (2MB) | m2 u16[16384][32]@14MB (1MB) | list@15MB (1MB)

__device__ inline u32 umin32(u32 a, u32 b) { return a < b ? a : b; }
__device__ inline u32 umax32(u32 a, u32 b) { return a > b ? a : b; }
__device__ inline u32 okey(float d) {
  u32 u = __float_as_uint(d);
  return (u >> 31) ? ~u : (u | 0x80000000u);
}
__device__ inline float dec(u32 key) {
  u32 u = (key & 0x80000000u) ? (key & 0x7FFFFFFFu) : ~key;
  return __uint_as_float(u);
}
__device__ inline u64 pack64(float d, unsigned col) {
  return ((u64)okey(d) << 32) | col;
}

// fused: ee (blocks 0..31), ff (32..95), xhT transpose+cvt (96..1119), ehT (1120..1631)
__global__ __launch_bounds__(256) void k_prep(const float* __restrict__ x,
                                              const float* __restrict__ e,
                                              float* __restrict__ Fv,
                                              float* __restrict__ eev,
                                              u32* __restrict__ eemax,
                                              f16* __restrict__ xhT,
                                              f16* __restrict__ ehT) {
#pragma clang fp contract(off)
  __shared__ float sm[64][65];
  const int bid = blockIdx.x, tid = threadIdx.x;
  if (bid < 32) {              // ||e_k||^2 (np sequential order, no contraction)
    int k = bid * 256 + tid;
    float s = 0.0f;
    for (int c = 0; c < 256; ++c) { float v = e[(size_t)c * KD + k]; float sq = v * v; s = s + sq; }
    eev[k] = s;
    atomicMax(eemax, __float_as_uint(s));
  } else if (bid < 96) {       // ||f_n||^2 (numpy pairwise, validated r1/r2)
    int n = (bid - 32) * 256 + tid;
    int b = n >> 10, hw = n & 1023;
    const float* px = x + ((size_t)b << 18) + hw;
    float sblk[2];
#pragma unroll
    for (int blk = 0; blk < 2; ++blk) {
      float r[8];
#pragma unroll
      for (int j = 0; j < 8; ++j) { float v = px[(size_t)(blk * 128 + j) << 10]; r[j] = v * v; }
      for (int i = 8; i < 128; i += 8) {
#pragma unroll
        for (int j = 0; j < 8; ++j) {
          float v = px[(size_t)(blk * 128 + i + j) << 10];
          float sq = v * v;
          r[j] = r[j] + sq;
        }
      }
      sblk[blk] = ((r[0] + r[1]) + (r[2] + r[3])) + ((r[4] + r[5]) + (r[6] + r[7]));
    }
    Fv[n] = sblk[0] + sblk[1];
  } else if (bid < 1120) {     // xhT[n][c] = (f16)x[b][c][hw]
    int t = bid - 96;
    int b = t >> 6, rem = t & 63;
    int hw0 = (rem >> 2) * 64, c0 = (rem & 3) * 64;
    int tx = tid & 63, ty = tid >> 6;
#pragma unroll
    for (int i = 0; i < 16; ++i) {
      int cl = i * 4 + ty;
      sm[cl][tx] = x[((size_t)(b * 256 + c0 + cl) << 10) + hw0 + tx];
    }
    __syncthreads();
#pragma unroll
    for (int i = 0; i < 16; ++i) {
      int hl = i * 4 + ty;
      xhT[(size_t)(b * 1024 + hw0 + hl) * 256 + c0 + tx] = (f16)sm[tx][hl];
    }
  } else {                     // ehT[k][c] = (f16)e[c][k]
    int t = bid - 1120;
    int k0 = (t >> 2) * 64, c0 = (t & 3) * 64;
    int tx = tid & 63, ty = tid >> 6;
#pragma unroll
    for (int i = 0; i < 16; ++i) {
      int cl = i * 4 + ty;
      sm[cl][tx] = e[(size_t)(c0 + cl) * KD + k0 + tx];
    }
    __syncthreads();
#pragma unroll
    for (int i = 0; i < 16; ++i) {
      int kl = i * 4 + ty;
      ehT[(size_t)(k0 + kl) * 256 + c0 + tx] = (f16)sm[tx][kl];
    }
  }
}

// LDS-free MFMA distance GEMM. WG = 128 rows x 256 cols (one chunk), 8 waves 2x4.
// Fragments loaded straight from xhT/ehT (16B/lane, 64B-coalesced per g-group).
// Epilogue: per-(row,chunk) top-2 of u32 packed keys (ordered-float | col8).
__global__ __launch_bounds__(512, 4) void k_gemm(const f16* __restrict__ xhT,
                                                 const f16* __restrict__ ehT,
                                                 const float* __restrict__ eev,
                                                 u32* __restrict__ m1p,
                                                 u16* __restrict__ m2p) {
  __shared__ u32 redm1[128][4];
  __shared__ u32 redm2[128][4];
  const int tid = threadIdx.x;
  const int lane = tid & 63, w = tid >> 6;
  const int wm = w >> 2, wn = w & 3;
  const int l15 = lane & 15, g = lane >> 4;
  const int chunk = blockIdx.x;                    // 0..31
  const int row0 = blockIdx.y * 128;
  const int col0 = chunk * 256 + wn * 64;

  f32x4 acc[4][4];
#pragma unroll
  for (int i = 0; i < 4; ++i)
#pragma unroll
    for (int j = 0; j < 4; ++j) acc[i][j] = (f32x4){0.f, 0.f, 0.f, 0.f};

  const f16* pa = xhT + (size_t)(row0 + wm * 64 + l15) * 256 + g * 8;
  const f16* pb = ehT + (size_t)(col0 + l15) * 256 + g * 8;
#pragma unroll
  for (int kk = 0; kk < 8; ++kk) {
    half8 af[4], bf[4];
#pragma unroll
    for (int mt = 0; mt < 4; ++mt) af[mt] = *(const half8*)(pa + mt * 16 * 256 + kk * 32);
#pragma unroll
    for (int nt = 0; nt < 4; ++nt) bf[nt] = *(const half8*)(pb + nt * 16 * 256 + kk * 32);
#pragma unroll
    for (int mt = 0; mt < 4; ++mt)
#pragma unroll
      for (int nt = 0; nt < 4; ++nt)
        acc[mt][nt] = __builtin_amdgcn_mfma_f32_16x16x32_f16(af[mt], bf[nt], acc[mt][nt], 0, 0, 0);
  }

  float eer[4]; u32 colb[4];
#pragma unroll
  for (int nt = 0; nt < 4; ++nt) {
    u32 cic = wn * 64 + nt * 16 + l15;             // col-in-chunk, 8 bits
    colb[nt] = cic;
    eer[nt] = eev[chunk * 256 + cic];
  }
#pragma unroll
  for (int mt = 0; mt < 4; ++mt) {
#pragma unroll
    for (int r = 0; r < 4; ++r) {
      u32 m1 = 0xFFFFFFFFu, m2 = 0xFFFFFFFFu;
#pragma unroll
      for (int nt = 0; nt < 4; ++nt) {
        float d = fmaf(-2.f, acc[mt][nt][r], eer[nt]);
        u32 kp = (okey(d) & 0xFFFFFF00u) | colb[nt];
        u32 t = umax32(m1, kp);
        m1 = umin32(m1, kp);
        m2 = umin32(m2, t);
      }
#pragma unroll
      for (int msk = 1; msk < 16; msk <<= 1) {
        u32 o1 = (u32)__shfl_xor((int)m1, msk, 64);
        u32 o2 = (u32)__shfl_xor((int)m2, msk, 64);
        u32 t = umax32(m1, o1);
        m1 = umin32(m1, o1);
        m2 = umin32(umin32(m2, o2), t);
      }
      if (l15 == 0) {
        int rl = wm * 64 + mt * 16 + g * 4 + r;
        redm1[rl][wn] = m1;
        redm2[rl][wn] = m2;
      }
    }
  }
  __syncthreads();
  if (tid < 128) {
    u32 m1 = 0xFFFFFFFFu, m2 = 0xFFFFFFFFu;
#pragma unroll
    for (int q = 0; q < 4; ++q) {
      u32 a = redm1[tid][q], b2 = redm2[tid][q];
      u32 t = umax32(m1, a);
      m1 = umin32(m1, a);
      m2 = umin32(m2, umin32(t, b2));
    }
    m1p[(size_t)(row0 + tid) * 32 + chunk] = m1;
    m2p[(size_t)(row0 + tid) * 32 + chunk] = (u16)(m2 >> 16);
  }
}

// per-row: global min over 32 chunk-top1s -> window; rescore top1 candidates
// inline (bit-exact chain); enqueue full-chunk tasks where top2 in window.
__global__ __launch_bounds__(256) void k_sel(const float* __restrict__ x,
                                             const float* __restrict__ e,
                                             const u32* __restrict__ m1p,
                                             const u16* __restrict__ m2p,
                                             const float* __restrict__ Fv,
                                             const float* __restrict__ eev,
                                             const u32* __restrict__ eemax,
                                             u64* __restrict__ best,
                                             u32* __restrict__ cnt,
                                             u32* __restrict__ list) {
  const int row = blockIdx.x * 4 + (threadIdx.x >> 6);
  const int lane = threadIdx.x & 63;
  u32 m1 = 0xFFFFFFFFu, m2k = 0xFFFFFFFFu;
  if (lane < 32) {
    m1 = m1p[(size_t)row * 32 + lane];
    m2k = ((u32)m2p[(size_t)row * 32 + lane]) << 16;   // round-down lower bound
  }
  u32 gk = m1;
#pragma unroll
  for (int msk = 1; msk < 64; msk <<= 1) gk = umin32(gk, (u32)__shfl_xor((int)gk, msk, 64));
  float F = Fv[row];
  float eps = 0x1p-9f * sqrtf(F * __uint_as_float(*eemax)) + 4e-4f;
  float thr = dec(gk) + 2.f * eps + 1e-4f;
  const int b = row >> 10, hw = row & 1023;
  if (lane < 32) {
    if (dec(m2k) <= thr) {
      u32 slot = atomicAdd(cnt, 1u);
      if (slot < LCAP) list[slot] = (u32)((row << 5) | lane);
      else {  // overflow fallback: inline full-chunk exact rescore (~never)
        for (int j = 0; j < 256; ++j) {
          int col = lane * 256 + j;
          float a = 0.f;
          for (int c = 0; c < 256; ++c)
            a = fmaf(x[((size_t)(b * 256 + c) << 10) + hw], e[(size_t)c * KD + col], a);
          float t = fmaf(-2.f, a, F);
          float d = t + eev[col];
          atomicMin(&best[row], pack64(d, (unsigned)col));
        }
      }
    }
    if (dec(m1) <= thr) {
      int col = lane * 256 + (int)(m1 & 255u);
      float a = 0.f;
      for (int c = 0; c < 256; ++c)
        a = fmaf(x[((size_t)(b * 256 + c) << 10) + hw], e[(size_t)c * KD + col], a);
      float t = fmaf(-2.f, a, F);
      float d = t + eev[col];
      atomicMin(&best[row], pack64(d, (unsigned)col));
    }
  }
}

// full-chunk exact rescore: wave per task, 4 cols/lane
__global__ __launch_bounds__(256) void k_chunk(const float* __restrict__ x,
                                               const float* __restrict__ e,
                                               const float* __restrict__ Fv,
                                               const float* __restrict__ eev,
                                               const u32* __restrict__ cnt,
                                               const u32* __restrict__ list,
                                               u64* __restrict__ best) {
  u32 n = *cnt; if (n > LCAP) n = LCAP;
  const int lane = threadIdx.x & 63;
  for (u32 t = blockIdx.x * 4 + (threadIdx.x >> 6); t < n; t += gridDim.x * 4) {
    u32 v = list[t];
    int row = (int)(v >> 5), ch = (int)(v & 31u);
    int b = row >> 10, hw = row & 1023;
    float F = Fv[row];
    int c0 = ch * 256 + lane;
    float a0 = 0.f, a1 = 0.f, a2 = 0.f, a3 = 0.f;
    for (int c = 0; c < 256; ++c) {
      float xv = x[((size_t)(b * 256 + c) << 10) + hw];
      const float* ep = e + (size_t)c * KD + c0;
      a0 = fmaf(xv, ep[0], a0);
      a1 = fmaf(xv, ep[64], a1);
      a2 = fmaf(xv, ep[128], a2);
      a3 = fmaf(xv, ep[192], a3);
    }
    float acc4[4] = {a0, a1, a2, a3};
#pragma unroll
    for (int q = 0; q < 4; ++q) {
      int col = c0 + q * 64;
      float t2 = fmaf(-2.f, acc4[q], F);
      float d = t2 + eev[col];
      atomicMin(&best[row], pack64(d, (unsigned)col));
    }
  }
}

// quantize + straight-through + diff partials + fused eind/counts
__global__ __launch_bounds__(256) void k_out(const float* __restrict__ x,
                                             const float* __restrict__ e,
                                             const u64* __restrict__ best,
                                             float* __restrict__ out,
                                             float* __restrict__ dpart,
                                             int* __restrict__ counts) {
  __shared__ float sd[256];
  int tid = threadIdx.x;
  float local = 0.0f;
  for (size_t i = (size_t)blockIdx.x * 256 + tid; i < 4194304ull; i += (size_t)gridDim.x * 256) {
    int hw = (int)(i & 1023);
    int c = (int)((i >> 10) & 255);
    int bb = (int)(i >> 18);
    int n = (bb << 10) + hw;
    u32 idx = (u32)(best[n] & 0xFFFFFFFFull);
    float xv = x[i];
    float q = e[(size_t)c * KD + idx];
    float qd = q - xv;
    out[i] = xv + qd;
    local += qd * qd;
    if (c == 0) {
      out[EIND_OFF + n] = (float)idx;
      atomicAdd(&counts[idx], 1);
    }
  }
  sd[tid] = local;
  __syncthreads();
  for (int s = 128; s > 0; s >>= 1) {
    if (tid < s) sd[tid] += sd[tid + s];
    __syncthreads();
  }
  if (tid == 0) dpart[blockIdx.x] = sd[0];
}

__global__ __launch_bounds__(256) void k_perp(const int* __restrict__ counts,
                                              const float* __restrict__ dpart,
                                              float* __restrict__ out) {
  __shared__ float sd[256];
  int tid = threadIdx.x;
  float s = 0.0f;
  for (int k = tid; k < KD; k += 256) {
    float p = (float)counts[k] * (1.0f / 16384.0f);
    s += p * logf(p + 1e-10f);
  }
  sd[tid] = s;
  __syncthreads();
  for (int t = 128; t > 0; t >>= 1) {
    if (tid < t) sd[tid] += sd[tid + t];
    __syncthreads();
  }
  float S = sd[0];
  __syncthreads();
  float d = 0.0f;
  for (int t = tid; t < 1024; t += 256) d += dpart[t];
  sd[tid] = d;
  __syncthreads();
  for (int t = 128; t > 0; t >>= 1) {
    if (tid < t) sd[tid] += sd[tid + t];
    __syncthreads();
  }
  if (tid == 0) {
    out[DIFF_OFF] = sd[0] * (1.0f / 4194304.0f);
    out[PERP_OFF] = expf(-S);
  }
}

extern "C" void kernel_launch(void* const* d_in, const int* in_sizes, int n_in,
                              void* d_out, int out_size, void* d_ws, size_t ws_size,
                              hipStream_t stream) {
  const float* x = (const float*)d_in[0];   // [16,256,32,32]
  const float* e = (const float*)d_in[1];   // [256,8192]
  float* out = (float*)d_out;
  char* dc = (char*)d_out;
  char* ws = (char*)d_ws;

  u64* best = (u64*)(ws);
  float* Fv = (float*)(ws + 131072);
  float* eev = (float*)(ws + 196608);
  int* counts = (int*)(ws + 229376);
  float* dpart = (float*)(ws + 262144);
  u32* eemax = (u32*)(ws + 266240);
  u32* cnt = (u32*)(ws + 266244);

  f16* xhT = (f16*)(dc);
  f16* ehT = (f16*)(dc + 8388608);
  u32* m1p = (u32*)(dc + 12582912);
  u16* m2p = (u16*)(dc + 14680064);
  u32* list = (u32*)(dc + 15728640);

  hipMemsetAsync(best, 0xFF, 131072, stream);
  hipMemsetAsync(counts, 0, 36872, stream);   // counts + dpart + eemax + cnt

  k_prep<<<1632, 256, 0, stream>>>(x, e, Fv, eev, eemax, xhT, ehT);
  k_gemm<<<dim3(32, 128), 512, 0, stream>>>(xhT, ehT, eev, m1p, m2p);
  k_sel<<<4096, 256, 0, stream>>>(x, e, m1p, m2p, Fv, eev, eemax, best, cnt, list);
  k_chunk<<<512, 256, 0, stream>>>(x, e, Fv, eev, cnt, list, best);
  k_out<<<1024, 256, 0, stream>>>(x, e, best, out, dpart, counts);
  k_perp<<<1, 256, 0, stream>>>(counts, dpart, out);
}

// Round 4
// 405.581 us; speedup vs baseline: 1.0439x; 1.0439x over previous
//
#include <hip/hip_runtime.h>

typedef _Float16 f16;
typedef f16 half8 __attribute__((ext_vector_type(8)));
typedef float f32x4 __attribute__((ext_vector_type(4)));
typedef unsigned long long u64;
typedef unsigned int u32;
typedef unsigned short u16;

#define KD 8192
#define DIFF_OFF 4194304
#define EIND_OFF 4194305
#define PERP_OFF 4210689
#define LCAP 1000000
#define ENC_S 42.0f      // t = (d' + 12) * 42  ->  [0, 1023]
#define ENC_B 12.0f

// ---- ws layout (bytes), total 299016 (< known-safe 331776) ----
// best u64[16384]@0 | Fv@131072 | eev@196608 | eesc@229376 |
// counts@262144 | dpart@294912 | eemax@299008 | cnt@299012
// ---- d_out scratch (dead before k_out writes) ----
// ehT f16[8192][256]@0 (4MB) | m1 u16[128][16384]@4MB (4MB)
// m2 u16[128][16384]@8MB (4MB) | list u32@12MB

__device__ inline u32 umin32(u32 a, u32 b) { return a < b ? a : b; }
__device__ inline u32 umax32(u32 a, u32 b) { return a > b ? a : b; }
__device__ inline u64 pack64(float d, unsigned col) {
  u32 u = __float_as_uint(d);
  u = (u >> 31) ? ~u : (u | 0x80000000u);
  return ((u64)u << 32) | col;
}
// exact distance chain — bit-identical to rounds 1-3 (validated absmax 0)
__device__ inline float exact_d(const float* __restrict__ x, const float* __restrict__ e,
                                int b, int hw, int col, float F, const float* __restrict__ eev) {
  float a = 0.f;
  for (int c = 0; c < 256; ++c)
    a = fmaf(x[((size_t)(b * 256 + c) << 10) + hw], e[(size_t)c * KD + col], a);
  float t = fmaf(-2.f, a, F);
  return t + eev[col];
}

// blocks 0..31: ee/eesc | 32..95: Fv | 96..607: ehT transpose
__global__ __launch_bounds__(256) void k_prep(const float* __restrict__ x,
                                              const float* __restrict__ e,
                                              float* __restrict__ Fv,
                                              float* __restrict__ eev,
                                              float* __restrict__ eesc,
                                              u32* __restrict__ eemax,
                                              f16* __restrict__ ehT) {
#pragma clang fp contract(off)
  __shared__ float sm[64][65];
  const int bid = blockIdx.x, tid = threadIdx.x;
  if (bid < 32) {              // ||e_k||^2, np sequential order
    int k = bid * 256 + tid;
    float s = 0.0f;
    for (int c = 0; c < 256; ++c) { float v = e[(size_t)c * KD + k]; float sq = v * v; s = s + sq; }
    eev[k] = s;
    eesc[k] = (s + ENC_B) * ENC_S;
    atomicMax(eemax, __float_as_uint(s));
  } else if (bid < 96) {       // ||f_n||^2, numpy pairwise (validated)
    int n = (bid - 32) * 256 + tid;
    int b = n >> 10, hw = n & 1023;
    const float* px = x + ((size_t)b << 18) + hw;
    float sblk[2];
#pragma unroll
    for (int blk = 0; blk < 2; ++blk) {
      float r[8];
#pragma unroll
      for (int j = 0; j < 8; ++j) { float v = px[(size_t)(blk * 128 + j) << 10]; r[j] = v * v; }
      for (int i = 8; i < 128; i += 8) {
#pragma unroll
        for (int j = 0; j < 8; ++j) {
          float v = px[(size_t)(blk * 128 + i + j) << 10];
          float sq = v * v;
          r[j] = r[j] + sq;
        }
      }
      sblk[blk] = ((r[0] + r[1]) + (r[2] + r[3])) + ((r[4] + r[5]) + (r[6] + r[7]));
    }
    Fv[n] = sblk[0] + sblk[1];
  } else {                     // ehT[k][c] = (f16)e[c][k]
    int t = bid - 96;
    int k0 = (t >> 2) * 64, c0 = (t & 3) * 64;
    int tx = tid & 63, ty = tid >> 6;
#pragma unroll
    for (int i = 0; i < 16; ++i) {
      int cl = i * 4 + ty;
      sm[cl][tx] = e[(size_t)(c0 + cl) * KD + k0 + tx];
    }
    __syncthreads();
#pragma unroll
    for (int i = 0; i < 16; ++i) {
      int kl = i * 4 + ty;
      ehT[(size_t)(k0 + kl) * 256 + c0 + tx] = (f16)sm[tx][kl];
    }
  }
}

// K-resident MFMA distance GEMM. Grid 256: half=bid&1 (XCD-parity -> B-half
// L2-resident per XCD), rowblk=bid>>1. 8 waves 2x4, wave-tile 64x64,
// 16 chunk-iters of 256 cols. A (64 rows x 256c fp16) lives in 128 VGPRs,
// loaded once straight from x (gather+cvt). B streamed from ehT, 2-deep.
// Epilogue: u16 key = (trunc((d'+12)*42) << 6) | col6; per-sub top1+top2.
__global__ __launch_bounds__(512, 2) void k_gemm(const float* __restrict__ x,
                                                 const f16* __restrict__ ehT,
                                                 const float* __restrict__ eesc,
                                                 u16* __restrict__ m1,
                                                 u16* __restrict__ m2) {
  const int tid = threadIdx.x;
  const int lane = tid & 63, w = tid >> 6;
  const int wm = w >> 2, wn = w & 3;
  const int l15 = lane & 15, g = lane >> 4;
  const int half = blockIdx.x & 1;
  const int rowblk = (int)blockIdx.x >> 1;
  const int row0 = rowblk * 128;
  const int b = rowblk >> 3;
  const int hw0 = (rowblk & 7) * 128;

  // ---- load A once: af[mt][kk], 128 VGPRs ----
  half8 af[4][8];
#pragma unroll
  for (int mt = 0; mt < 4; ++mt) {
    const float* px = x + ((size_t)b << 18) + (hw0 + wm * 64 + mt * 16 + l15);
#pragma unroll
    for (int kk = 0; kk < 8; ++kk) {
      half8 h;
#pragma unroll
      for (int j = 0; j < 8; ++j)
        h[j] = (f16)px[(size_t)(kk * 32 + g * 8 + j) << 10];
      af[mt][kk] = h;
    }
  }

  const int colw = half * 4096 + wn * 64;          // + chunk*256
  const f16* pb0 = ehT + (size_t)(colw + l15) * 256 + g * 8;
  const int l15c = l15;

  for (int chunk = 0; chunk < 16; ++chunk) {
    const f16* pb = pb0 + (size_t)chunk * 256 * 256;
    f32x4 acc[4][4];
#pragma unroll
    for (int i = 0; i < 4; ++i)
#pragma unroll
      for (int j = 0; j < 4; ++j) acc[i][j] = (f32x4){0.f, 0.f, 0.f, 0.f};

    half8 bf[2][4];
#pragma unroll
    for (int nt = 0; nt < 4; ++nt) bf[0][nt] = *(const half8*)(pb + nt * 16 * 256);
#pragma unroll
    for (int kk = 0; kk < 8; ++kk) {
      if (kk < 7) {
#pragma unroll
        for (int nt = 0; nt < 4; ++nt)
          bf[(kk + 1) & 1][nt] = *(const half8*)(pb + nt * 16 * 256 + (kk + 1) * 32);
      }
#pragma unroll
      for (int mt = 0; mt < 4; ++mt)
#pragma unroll
        for (int nt = 0; nt < 4; ++nt)
          acc[mt][nt] = __builtin_amdgcn_mfma_f32_16x16x32_f16(af[mt][kk], bf[kk & 1][nt], acc[mt][nt], 0, 0, 0);
    }

    // epilogue: per-sub(64-col) top1(+col6) / top2 over u16 keys
    float esc[4];
#pragma unroll
    for (int nt = 0; nt < 4; ++nt)
      esc[nt] = eesc[half * 4096 + chunk * 256 + wn * 64 + nt * 16 + l15];
    const int sub = half * 64 + chunk * 4 + wn;
#pragma unroll
    for (int mt = 0; mt < 4; ++mt) {
      u32 p1lo = 0, p1hi = 0, p2lo = 0, p2hi = 0;
#pragma unroll
      for (int r = 0; r < 4; ++r) {
        u32 k[4];
#pragma unroll
        for (int nt = 0; nt < 4; ++nt) {
          float t = fmaf(acc[mt][nt][r], -2.0f * ENC_S, esc[nt]);
          u32 u = (u32)t;                           // trunc, in [0,1023]
          k[nt] = (u << 6) + (u32)(nt * 16 + l15c); // key | col-in-sub
        }
        u32 a = umin32(k[0], k[1]), bb = umax32(k[0], k[1]);
        u32 c = umin32(k[2], k[3]), d2 = umax32(k[2], k[3]);
        u32 s1 = umin32(a, c);
        u32 s2 = umin32(umax32(a, c), umin32(bb, d2));
#pragma unroll
        for (int msk = 1; msk < 16; msk <<= 1) {
          u32 o1 = (u32)__shfl_xor((int)s1, msk, 64);
          u32 o2 = (u32)__shfl_xor((int)s2, msk, 64);
          u32 t2 = umax32(s1, o1);
          s1 = umin32(s1, o1);
          s2 = umin32(umin32(s2, o2), t2);
        }
        if (r & 1) { p1hi |= s1 << 16; p2hi |= s2 << 16; }
        else if (r == 0) { p1lo = s1; p2lo = s2; }
        else { p1lo = p1lo; }
        if (r == 2) { p1hi = s1; p2hi = s2; }
        if (r == 1) { p1lo |= s1 << 16; p2lo |= s2 << 16; }
      }
      if (l15 == 0) {
        size_t base = (size_t)sub * 16384 + (row0 + wm * 64 + mt * 16 + g * 4);
        *(uint2*)(m1 + base) = make_uint2(p1lo, p1hi);
        *(uint2*)(m2 + base) = make_uint2(p2lo, p2hi);
      }
    }
  }
}

// per row (1 wave): gmin over 128 sub-top1s -> window; exact 1-col rescore of
// in-window sub-top1 cols; enqueue full-sub tasks where sub-top2 in window.
__global__ __launch_bounds__(256) void k_sel(const float* __restrict__ x,
                                             const float* __restrict__ e,
                                             const u16* __restrict__ m1,
                                             const u16* __restrict__ m2,
                                             const float* __restrict__ Fv,
                                             const float* __restrict__ eev,
                                             const u32* __restrict__ eemax,
                                             u64* __restrict__ best,
                                             u32* __restrict__ cnt,
                                             u32* __restrict__ list) {
  const int row = blockIdx.x * 4 + (threadIdx.x >> 6);
  const int lane = threadIdx.x & 63;
  const u32 k0v = m1[(size_t)lane * 16384 + row];
  const u32 k1v = m1[(size_t)(lane + 64) * 16384 + row];
  const u32 s0v = m2[(size_t)lane * 16384 + row];
  const u32 s1v = m2[(size_t)(lane + 64) * 16384 + row];
  u32 gk = umin32(k0v, k1v);
#pragma unroll
  for (int msk = 1; msk < 64; msk <<= 1) gk = umin32(gk, (u32)__shfl_xor((int)gk, msk, 64));
  const float F = Fv[row];
  const float step = 1.0f / ENC_S;
  const float eps = 0x1p-9f * sqrtf(F * __uint_as_float(*eemax)) + 4e-4f;
  const float gdec = (float)(gk >> 6) * step - ENC_B;
  const float thr = gdec + 2.f * eps + 3.f * step;
  const float thru = (thr + ENC_B) * ENC_S;        // compare in u10 domain
  const int b = row >> 10, hw = row & 1023;
#pragma unroll
  for (int h2 = 0; h2 < 2; ++h2) {
    const u32 key = h2 ? k1v : k0v;
    const u32 key2 = h2 ? s1v : s0v;
    const int sub = lane + h2 * 64;
    const bool f1 = ((float)(key >> 6) <= thru);
    if (__any(f1)) {
      if (f1) {
        int col = sub * 64 + (int)(key & 63u);
        float d = exact_d(x, e, b, hw, col, F, eev);
        atomicMin(&best[row], pack64(d, (unsigned)col));
      }
    }
    if ((float)(key2 >> 6) <= thru) {
      u32 slot = atomicAdd(cnt, 1u);
      if (slot < LCAP) list[slot] = (u32)((row << 7) | sub);
      else {
        for (int j = 0; j < 64; ++j) {
          int col = sub * 64 + j;
          float d = exact_d(x, e, b, hw, col, F, eev);
          atomicMin(&best[row], pack64(d, (unsigned)col));
        }
      }
    }
  }
}

// full-sub exact rescore: wave per task, lane = col-in-sub
__global__ __launch_bounds__(256) void k_chunk(const float* __restrict__ x,
                                               const float* __restrict__ e,
                                               const float* __restrict__ Fv,
                                               const float* __restrict__ eev,
                                               const u32* __restrict__ cnt,
                                               const u32* __restrict__ list,
                                               u64* __restrict__ best) {
  u32 n = *cnt; if (n > LCAP) n = LCAP;
  const int lane = threadIdx.x & 63;
  for (u32 t = blockIdx.x * 4 + (threadIdx.x >> 6); t < n; t += gridDim.x * 4) {
    u32 v = list[t];
    int row = (int)(v >> 7), sub = (int)(v & 127u);
    int b = row >> 10, hw = row & 1023;
    int col = sub * 64 + lane;
    float d = exact_d(x, e, b, hw, col, Fv[row], eev);
    atomicMin(&best[row], pack64(d, (unsigned)col));
  }
}

// quantize + straight-through + diff partials + eind/counts
__global__ __launch_bounds__(256) void k_out(const float* __restrict__ x,
                                             const float* __restrict__ e,
                                             const u64* __restrict__ best,
                                             float* __restrict__ out,
                                             float* __restrict__ dpart,
                                             int* __restrict__ counts) {
  __shared__ float sd[256];
  int tid = threadIdx.x;
  float local = 0.0f;
  for (size_t i = (size_t)blockIdx.x * 256 + tid; i < 4194304ull; i += (size_t)gridDim.x * 256) {
    int hw = (int)(i & 1023);
    int c = (int)((i >> 10) & 255);
    int bb = (int)(i >> 18);
    int n = (bb << 10) + hw;
    u32 idx = (u32)(best[n] & 0xFFFFFFFFull);
    float xv = x[i];
    float q = e[(size_t)c * KD + idx];
    float qd = q - xv;
    out[i] = xv + qd;
    local += qd * qd;
    if (c == 0) {
      out[EIND_OFF + n] = (float)idx;
      atomicAdd(&counts[idx], 1);
    }
  }
  sd[tid] = local;
  __syncthreads();
  for (int s = 128; s > 0; s >>= 1) {
    if (tid < s) sd[tid] += sd[tid + s];
    __syncthreads();
  }
  if (tid == 0) dpart[blockIdx.x] = sd[0];
}

__global__ __launch_bounds__(256) void k_perp(const int* __restrict__ counts,
                                              const float* __restrict__ dpart,
                                              float* __restrict__ out) {
  __shared__ float sd[256];
  int tid = threadIdx.x;
  float s = 0.0f;
  for (int k = tid; k < KD; k += 256) {
    float p = (float)counts[k] * (1.0f / 16384.0f);
    s += p * logf(p + 1e-10f);
  }
  sd[tid] = s;
  __syncthreads();
  for (int t = 128; t > 0; t >>= 1) {
    if (tid < t) sd[tid] += sd[tid + t];
    __syncthreads();
  }
  float S = sd[0];
  __syncthreads();
  float d = 0.0f;
  for (int t = tid; t < 1024; t += 256) d += dpart[t];
  sd[tid] = d;
  __syncthreads();
  for (int t = 128; t > 0; t >>= 1) {
    if (tid < t) sd[tid] += sd[tid + t];
    __syncthreads();
  }
  if (tid == 0) {
    out[DIFF_OFF] = sd[0] * (1.0f / 4194304.0f);
    out[PERP_OFF] = expf(-S);
  }
}

extern "C" void kernel_launch(void* const* d_in, const int* in_sizes, int n_in,
                              void* d_out, int out_size, void* d_ws, size_t ws_size,
                              hipStream_t stream) {
  const float* x = (const float*)d_in[0];   // [16,256,32,32]
  const float* e = (const float*)d_in[1];   // [256,8192]
  float* out = (float*)d_out;
  char* dc = (char*)d_out;
  char* ws = (char*)d_ws;

  u64* best = (u64*)(ws);
  float* Fv = (float*)(ws + 131072);
  float* eev = (float*)(ws + 196608);
  float* eesc = (float*)(ws + 229376);
  int* counts = (int*)(ws + 262144);
  float* dpart = (float*)(ws + 294912);
  u32* eemax = (u32*)(ws + 299008);
  u32* cnt = (u32*)(ws + 299012);

  f16* ehT = (f16*)(dc);
  u16* m1 = (u16*)(dc + 4194304);
  u16* m2 = (u16*)(dc + 8388608);
  u32* list = (u32*)(dc + 12582912);

  hipMemsetAsync(best, 0xFF, 131072, stream);
  hipMemsetAsync(counts, 0, 36872, stream);   // counts+dpart+eemax+cnt

  k_prep<<<608, 256, 0, stream>>>(x, e, Fv, eev, eesc, eemax, ehT);
  k_gemm<<<256, 512, 0, stream>>>(x, ehT, eesc, m1, m2);
  k_sel<<<4096, 256, 0, stream>>>(x, e, m1, m2, Fv, eev, eemax, best, cnt, list);
  k_chunk<<<1024, 256, 0, stream>>>(x, e, Fv, eev, cnt, list, best);
  k_out<<<1024, 256, 0, stream>>>(x, e, best, out, dpart, counts);
  k_perp<<<1, 256, 0, stream>>>(counts, dpart, out);
}

// Round 5
// 372.631 us; speedup vs baseline: 1.1362x; 1.0884x over previous
//
#include <hip/hip_runtime.h>

typedef _Float16 f16;
typedef f16 half8 __attribute__((ext_vector_type(8)));
typedef float f32x4 __attribute__((ext_vector_type(4)));
typedef unsigned long long u64;
typedef unsigned int u32;
typedef unsigned short u16;

#define KD 8192
#define DIFF_OFF 4194304
#define EIND_OFF 4194305
#define PERP_OFF 4210689
#define LCAP 1000000

// ---- ws layout (bytes) ----
// best u64[16384]@0 | Fv@131072 | eev@196608 | counts@229376 | dpart@262144 |
// eemax@266240 | cnt@266244
// ---- d_out scratch (all dead before k_out/k_perp write) ----
// ehT f16[8192][256]@0 (4MB) | m1 u32[16384][32]@4MB (2MB) |
// m2 u16[16384][32]@6MB (1MB) | list u32[1M]@7MB (4MB)

__device__ inline u32 umin32(u32 a, u32 b) { return a < b ? a : b; }
__device__ inline u32 umax32(u32 a, u32 b) { return a > b ? a : b; }
__device__ inline u32 okey(float d) {
  u32 u = __float_as_uint(d);
  return (u >> 31) ? ~u : (u | 0x80000000u);
}
__device__ inline float dec(u32 key) {
  u32 u = (key & 0x80000000u) ? (key & 0x7FFFFFFFu) : ~key;
  return __uint_as_float(u);
}
__device__ inline u64 pack64(float d, unsigned col) {
  return ((u64)okey(d) << 32) | col;
}
// exact distance chain — bit-identical to rounds 1-4 (validated absmax 0)
__device__ inline float exact_d(const float* __restrict__ x, const float* __restrict__ e,
                                int b, int hw, int col, float F, const float* __restrict__ eev) {
  float a = 0.f;
#pragma unroll 8
  for (int c = 0; c < 256; ++c)
    a = fmaf(x[((size_t)(b * 256 + c) << 10) + hw], e[(size_t)c * KD + col], a);
  float t = fmaf(-2.f, a, F);
  return t + eev[col];
}

// blocks 0..31: ee | 32..95: Fv | 96..607: ehT transpose
__global__ __launch_bounds__(256) void k_prep(const float* __restrict__ x,
                                              const float* __restrict__ e,
                                              float* __restrict__ Fv,
                                              float* __restrict__ eev,
                                              u32* __restrict__ eemax,
                                              f16* __restrict__ ehT) {
#pragma clang fp contract(off)
  __shared__ float sm[64][65];
  const int bid = blockIdx.x, tid = threadIdx.x;
  if (bid < 32) {              // ||e_k||^2, np sequential order (validated)
    int k = bid * 256 + tid;
    float s = 0.0f;
    for (int c = 0; c < 256; ++c) { float v = e[(size_t)c * KD + k]; float sq = v * v; s = s + sq; }
    eev[k] = s;
    atomicMax(eemax, __float_as_uint(s));
  } else if (bid < 96) {       // ||f_n||^2, numpy pairwise (validated)
    int n = (bid - 32) * 256 + tid;
    int b = n >> 10, hw = n & 1023;
    const float* px = x + ((size_t)b << 18) + hw;
    float sblk[2];
#pragma unroll
    for (int blk = 0; blk < 2; ++blk) {
      float r[8];
#pragma unroll
      for (int j = 0; j < 8; ++j) { float v = px[(size_t)(blk * 128 + j) << 10]; r[j] = v * v; }
      for (int i = 8; i < 128; i += 8) {
#pragma unroll
        for (int j = 0; j < 8; ++j) {
          float v = px[(size_t)(blk * 128 + i + j) << 10];
          float sq = v * v;
          r[j] = r[j] + sq;
        }
      }
      sblk[blk] = ((r[0] + r[1]) + (r[2] + r[3])) + ((r[4] + r[5]) + (r[6] + r[7]));
    }
    Fv[n] = sblk[0] + sblk[1];
  } else {                     // ehT[k][c] = (f16)e[c][k]
    int t = bid - 96;
    int k0 = (t >> 2) * 64, c0 = (t & 3) * 64;
    int tx = tid & 63, ty = tid >> 6;
#pragma unroll
    for (int i = 0; i < 16; ++i) {
      int cl = i * 4 + ty;
      sm[cl][tx] = e[(size_t)(c0 + cl) * KD + k0 + tx];
    }
    __syncthreads();
#pragma unroll
    for (int i = 0; i < 16; ++i) {
      int kl = i * 4 + ty;
      ehT[(size_t)(k0 + kl) * 256 + c0 + tx] = (f16)sm[tx][kl];
    }
  }
}

// K-resident MFMA distance GEMM, LDS-free. Grid 512 = 256 rowblks(64r) x 2
// halves (half = bid&1 -> XCD parity keeps each 2MB ehT half L2-resident).
// 8 waves = wm(2) x wn(4); wave-tile 32r x 64c x 16 chunks.
// Epilogue: running top1/top2 per (row, sub=256 cols) with fp32 ordered keys
// (col8 in low bits), butterfly-folded every 4 chunks -> m1 u32 / m2 u16.
__global__ __launch_bounds__(512) void k_gemm(const float* __restrict__ x,
                                              const f16* __restrict__ ehT,
                                              const float* __restrict__ eev,
                                              u32* __restrict__ m1,
                                              u16* __restrict__ m2) {
  const int tid = threadIdx.x;
  const int lane = tid & 63, w = tid >> 6;
  const int wm = w >> 2, wn = w & 3;
  const int l15 = lane & 15, g = lane >> 4;
  const int half = blockIdx.x & 1;
  const int rowblk = (int)blockIdx.x >> 1;
  const int row0 = rowblk * 64;
  const int b = rowblk >> 4;
  const int hw0 = (rowblk & 15) * 64;

  // A resident: af[mt][kk] = 64 VGPRs
  half8 af[2][8];
#pragma unroll
  for (int mt = 0; mt < 2; ++mt) {
    const float* px = x + ((size_t)b << 18) + (hw0 + wm * 32 + mt * 16 + l15);
#pragma unroll
    for (int kk = 0; kk < 8; ++kk) {
      half8 h;
#pragma unroll
      for (int j = 0; j < 8; ++j)
        h[j] = (f16)px[(size_t)(kk * 32 + g * 8 + j) << 10];
      af[mt][kk] = h;
    }
  }

  const int colbase = half * 4096 + wn * 64;
  const f16* pb0 = ehT + (size_t)(colbase + l15) * 256 + g * 8;

  u32 s1[2][4], s2[2][4];
#pragma unroll
  for (int mt = 0; mt < 2; ++mt)
#pragma unroll
    for (int r = 0; r < 4; ++r) { s1[mt][r] = 0xFFFFFFFFu; s2[mt][r] = 0xFFFFFFFFu; }

  for (int chunk = 0; chunk < 16; ++chunk) {
    const f16* pb = pb0 + (size_t)chunk * 256 * 256;
    float ee4[4];
#pragma unroll
    for (int nt = 0; nt < 4; ++nt)
      ee4[nt] = eev[colbase + chunk * 256 + nt * 16 + l15];

    f32x4 acc[2][4];
#pragma unroll
    for (int i = 0; i < 2; ++i)
#pragma unroll
      for (int j = 0; j < 4; ++j) acc[i][j] = (f32x4){0.f, 0.f, 0.f, 0.f};

    half8 bf[2][4];
#pragma unroll
    for (int nt = 0; nt < 4; ++nt) bf[0][nt] = *(const half8*)(pb + nt * 4096);
#pragma unroll
    for (int kk = 0; kk < 8; ++kk) {
      if (kk < 7) {
#pragma unroll
        for (int nt = 0; nt < 4; ++nt)
          bf[(kk + 1) & 1][nt] = *(const half8*)(pb + nt * 4096 + (kk + 1) * 32);
      }
#pragma unroll
      for (int mt = 0; mt < 2; ++mt)
#pragma unroll
        for (int nt = 0; nt < 4; ++nt)
          acc[mt][nt] = __builtin_amdgcn_mfma_f32_16x16x32_f16(af[mt][kk], bf[kk & 1][nt], acc[mt][nt], 0, 0, 0);
    }

    // running top-2 update (fp32 ordered keys, col8 = i2|nt|l15 in low bits)
    const u32 i2 = (u32)(chunk & 3);
#pragma unroll
    for (int mt = 0; mt < 2; ++mt) {
#pragma unroll
      for (int r = 0; r < 4; ++r) {
#pragma unroll
        for (int nt = 0; nt < 4; ++nt) {
          float d = fmaf(-2.f, acc[mt][nt][r], ee4[nt]);
          u32 k = (okey(d) & 0xFFFFFF00u) | (i2 << 6) | ((u32)nt << 4) | (u32)l15;
          u32 t = umax32(s1[mt][r], k);
          s1[mt][r] = umin32(s1[mt][r], k);
          s2[mt][r] = umin32(s2[mt][r], t);
        }
      }
    }

    if ((chunk & 3) == 3) {   // group end: fold over 16 cols, store, reset
      const int cg = chunk >> 2;
      const int sidx = half * 16 + wn * 4 + cg;
      const int rr = l15 & 3;
#pragma unroll
      for (int mt = 0; mt < 2; ++mt) {
#pragma unroll
        for (int r = 0; r < 4; ++r) {
#pragma unroll
          for (int msk = 1; msk < 16; msk <<= 1) {
            u32 o1 = (u32)__shfl_xor((int)s1[mt][r], msk, 64);
            u32 o2 = (u32)__shfl_xor((int)s2[mt][r], msk, 64);
            u32 t = umax32(s1[mt][r], o1);
            s1[mt][r] = umin32(s1[mt][r], o1);
            s2[mt][r] = umin32(umin32(s2[mt][r], o2), t);
          }
        }
        u32 v1 = rr == 0 ? s1[mt][0] : rr == 1 ? s1[mt][1] : rr == 2 ? s1[mt][2] : s1[mt][3];
        u32 v2 = rr == 0 ? s2[mt][0] : rr == 1 ? s2[mt][1] : rr == 2 ? s2[mt][2] : s2[mt][3];
        int row = row0 + wm * 32 + mt * 16 + g * 4 + rr;
        if (l15 < 4) {
          m1[(size_t)row * 32 + sidx] = v1;
        } else if (l15 < 8) {
          float d2 = dec(v2 & 0xFFFFFF00u);          // lower bound of sub-top2
          float tq = fminf(fmaxf((d2 + 10.f) * 4096.f, 0.f), 65535.f);
          m2[(size_t)row * 32 + sidx] = (u16)(u32)tq;
        }
#pragma unroll
        for (int r = 0; r < 4; ++r) { s1[mt][r] = 0xFFFFFFFFu; s2[mt][r] = 0xFFFFFFFFu; }
      }
    }
  }
}

// one wave per row: coalesced m1/m2 read, window test, direct write when
// unambiguous; else exact rescore of in-window sub-top1s + enqueue subs
// whose top2 is in-window.
__global__ __launch_bounds__(256) void k_sel(const float* __restrict__ x,
                                             const float* __restrict__ e,
                                             const u32* __restrict__ m1,
                                             const u16* __restrict__ m2,
                                             const float* __restrict__ Fv,
                                             const float* __restrict__ eev,
                                             const u32* __restrict__ eemax,
                                             u64* __restrict__ best,
                                             u32* __restrict__ cnt,
                                             u32* __restrict__ list) {
  const int row = blockIdx.x * 4 + (threadIdx.x >> 6);
  const int lane = threadIdx.x & 63;
  u32 m1v = 0xFFFFFFFFu;
  u32 m2v = 0xFFFFu;
  if (lane < 32) {
    m1v = m1[(size_t)row * 32 + lane];
    m2v = (u32)m2[(size_t)row * 32 + lane];
  }
  u32 gk = m1v;
#pragma unroll
  for (int msk = 1; msk < 64; msk <<= 1) gk = umin32(gk, (u32)__shfl_xor((int)gk, msk, 64));
  const float F = Fv[row];
  const float eps = 0x1p-9f * sqrtf(F * __uint_as_float(*eemax)) + 4e-4f;
  const float thr = dec(gk & 0xFFFFFF00u) + 2.f * eps + 5e-4f;

  const bool f1 = (lane < 32) && (dec(m1v & 0xFFFFFF00u) <= thr);
  const bool trig = (lane < 32) && ((float)m2v * (1.0f / 4096.0f) - 10.f <= thr);
  const u64 bal = __ballot(f1);
  const bool anyt = __any(trig);

  // decode this lane's candidate column
  const int hf = lane >> 4, wnn = (lane >> 2) & 3, cg = lane & 3;
  const u32 c8 = m1v & 255u;
  const int col = hf * 4096 + (cg * 4 + (int)(c8 >> 6)) * 256 + wnn * 64 +
                  (int)((c8 >> 4) & 3u) * 16 + (int)(c8 & 15u);
  const int b = row >> 10, hw = row & 1023;

  if (__popcll(bal) == 1 && !anyt) {
    if (f1) best[row] = (u64)(unsigned)col;        // unambiguous: key 0
  } else {
    if (f1) {
      float d = exact_d(x, e, b, hw, col, F, eev);
      atomicMin(&best[row], pack64(d, (unsigned)col));
    }
    if (trig) {
      u32 slot = atomicAdd(cnt, 1u);
      if (slot < LCAP) list[slot] = (u32)((row << 5) | lane);
      else {   // overflow fallback (correctness only, ~never)
        for (int j = 0; j < 256; ++j) {
          int cj = hf * 4096 + (cg * 4 + (j >> 6)) * 256 + wnn * 64 + (j & 63);
          float d = exact_d(x, e, b, hw, cj, F, eev);
          atomicMin(&best[row], pack64(d, (unsigned)cj));
        }
      }
    }
  }
}

// full-sub (256-col) exact rescore: wave per task, 4 cols/lane sharing x loads
__global__ __launch_bounds__(256) void k_chunk(const float* __restrict__ x,
                                               const float* __restrict__ e,
                                               const float* __restrict__ Fv,
                                               const float* __restrict__ eev,
                                               const u32* __restrict__ cnt,
                                               const u32* __restrict__ list,
                                               u64* __restrict__ best) {
  u32 n = *cnt; if (n > LCAP) n = LCAP;
  const int lane = threadIdx.x & 63;
  for (u32 t = blockIdx.x * 4 + (threadIdx.x >> 6); t < n; t += gridDim.x * 4) {
    u32 v = list[t];
    int row = (int)(v >> 5), s = (int)(v & 31u);
    int hf = s >> 4, wnn = (s >> 2) & 3, cg = s & 3;
    int b = row >> 10, hw = row & 1023;
    float F = Fv[row];
    int base = hf * 4096 + cg * 4 * 256 + wnn * 64 + lane;
    float a0 = 0.f, a1 = 0.f, a2 = 0.f, a3 = 0.f;
#pragma unroll 8
    for (int c = 0; c < 256; ++c) {
      float xv = x[((size_t)(b * 256 + c) << 10) + hw];
      const float* ep = e + (size_t)c * KD + base;
      a0 = fmaf(xv, ep[0], a0);
      a1 = fmaf(xv, ep[256], a1);
      a2 = fmaf(xv, ep[512], a2);
      a3 = fmaf(xv, ep[768], a3);
    }
    float acc4[4] = {a0, a1, a2, a3};
#pragma unroll
    for (int q = 0; q < 4; ++q) {
      int col = base + q * 256;
      float t2 = fmaf(-2.f, acc4[q], F);
      float d = t2 + eev[col];
      atomicMin(&best[row], pack64(d, (unsigned)col));
    }
  }
}

// quantize + straight-through + diff partials + eind/counts
__global__ __launch_bounds__(256) void k_out(const float* __restrict__ x,
                                             const float* __restrict__ e,
                                             const u64* __restrict__ best,
                                             float* __restrict__ out,
                                             float* __restrict__ dpart,
                                             int* __restrict__ counts) {
  __shared__ float sd[256];
  int tid = threadIdx.x;
  float local = 0.0f;
  for (size_t i = (size_t)blockIdx.x * 256 + tid; i < 4194304ull; i += (size_t)gridDim.x * 256) {
    int hw = (int)(i & 1023);
    int c = (int)((i >> 10) & 255);
    int bb = (int)(i >> 18);
    int n = (bb << 10) + hw;
    u32 idx = (u32)(best[n] & 0xFFFFFFFFull);
    float xv = x[i];
    float q = e[(size_t)c * KD + idx];
    float qd = q - xv;
    out[i] = xv + qd;
    local += qd * qd;
    if (c == 0) {
      out[EIND_OFF + n] = (float)idx;
      atomicAdd(&counts[idx], 1);
    }
  }
  sd[tid] = local;
  __syncthreads();
  for (int s = 128; s > 0; s >>= 1) {
    if (tid < s) sd[tid] += sd[tid + s];
    __syncthreads();
  }
  if (tid == 0) dpart[blockIdx.x] = sd[0];
}

__global__ __launch_bounds__(256) void k_perp(const int* __restrict__ counts,
                                              const float* __restrict__ dpart,
                                              float* __restrict__ out) {
  __shared__ float sd[256];
  int tid = threadIdx.x;
  float s = 0.0f;
  for (int k = tid; k < KD; k += 256) {
    float p = (float)counts[k] * (1.0f / 16384.0f);
    s += p * logf(p + 1e-10f);
  }
  sd[tid] = s;
  __syncthreads();
  for (int t = 128; t > 0; t >>= 1) {
    if (tid < t) sd[tid] += sd[tid + t];
    __syncthreads();
  }
  float S = sd[0];
  __syncthreads();
  float d = 0.0f;
  for (int t = tid; t < 1024; t += 256) d += dpart[t];
  sd[tid] = d;
  __syncthreads();
  for (int t = 128; t > 0; t >>= 1) {
    if (tid < t) sd[tid] += sd[tid + t];
    __syncthreads();
  }
  if (tid == 0) {
    out[DIFF_OFF] = sd[0] * (1.0f / 4194304.0f);
    out[PERP_OFF] = expf(-S);
  }
}

extern "C" void kernel_launch(void* const* d_in, const int* in_sizes, int n_in,
                              void* d_out, int out_size, void* d_ws, size_t ws_size,
                              hipStream_t stream) {
  const float* x = (const float*)d_in[0];   // [16,256,32,32]
  const float* e = (const float*)d_in[1];   // [256,8192]
  float* out = (float*)d_out;
  char* dc = (char*)d_out;
  char* ws = (char*)d_ws;

  u64* best = (u64*)(ws);
  float* Fv = (float*)(ws + 131072);
  float* eev = (float*)(ws + 196608);
  int* counts = (int*)(ws + 229376);
  float* dpart = (float*)(ws + 262144);
  u32* eemax = (u32*)(ws + 266240);
  u32* cnt = (u32*)(ws + 266244);

  f16* ehT = (f16*)(dc);
  u32* m1 = (u32*)(dc + 4194304);
  u16* m2 = (u16*)(dc + 6291456);
  u32* list = (u32*)(dc + 7340032);

  hipMemsetAsync(best, 0xFF, 131072, stream);
  hipMemsetAsync(counts, 0, 36872, stream);   // counts+dpart+eemax+cnt

  k_prep<<<608, 256, 0, stream>>>(x, e, Fv, eev, eemax, ehT);
  k_gemm<<<512, 512, 0, stream>>>(x, ehT, eev, m1, m2);
  k_sel<<<4096, 256, 0, stream>>>(x, e, m1, m2, Fv, eev, eemax, best, cnt, list);
  k_chunk<<<1024, 256, 0, stream>>>(x, e, Fv, eev, cnt, list, best);
  k_out<<<1024, 256, 0, stream>>>(x, e, best, out, dpart, counts);
  k_perp<<<1, 256, 0, stream>>>(counts, dpart, out);
}